// Round 9
// baseline (444.440 us; speedup 1.0000x reference)
//
#include <hip/hip_runtime.h>
#include <stdint.h>

#define D_MODEL 1024
#define NHEAD   16
#define HDIM    64
#define FFDIM   4096
#define BATCH   4
#define SEQ     2048
#define ROWS    (BATCH*SEQ)   // 8192

typedef unsigned short u16;
typedef __bf16 bf16_t;
typedef bf16_t bf16x8 __attribute__((ext_vector_type(8)));
typedef float  f32x4  __attribute__((ext_vector_type(4)));
typedef float  f32x16 __attribute__((ext_vector_type(16)));

#define SCQ 0.18033688011112042f   // 0.125 * log2(e) — folded into Q at QKV epilogue

__device__ __forceinline__ u16 f2bf(float f) {
  union { float f; unsigned u; } v; v.f = f;
  unsigned r = v.u + 0x7fffu + ((v.u >> 16) & 1u);
  return (u16)(r >> 16);
}

__device__ __forceinline__ void gl2lds16(const void* g, void* l) {
  __builtin_amdgcn_global_load_lds((const __attribute__((address_space(1))) void*)g,
                                   (__attribute__((address_space(3))) void*)l, 16, 0, 0);
}

#define MFMA_BF16(a, b, c) __builtin_amdgcn_mfma_f32_16x16x32_bf16((a), (b), (c), 0, 0, 0)
#define MFMA32(a, b, c)    __builtin_amdgcn_mfma_f32_32x32x16_bf16((a), (b), (c), 0, 0, 0)
#define EXP2(x) __builtin_amdgcn_exp2f(x)

__device__ __forceinline__ bf16x8 mk8(unsigned a, unsigned b, unsigned c, unsigned d) {
  union { unsigned u[4]; bf16x8 v; } t;
  t.u[0] = a; t.u[1] = b; t.u[2] = c; t.u[3] = d;
  return t.v;
}

// ---------------- LayerNorm (fp32 in -> bf16 out) ----------------
__global__ __launch_bounds__(256) void ln_kernel(const float* __restrict__ x,
                                                 const float* __restrict__ g,
                                                 const float* __restrict__ be,
                                                 u16* __restrict__ out) {
  __shared__ float red[10];
  int row = blockIdx.x;
  int t = threadIdx.x;
  const float* xr = x + (size_t)row * D_MODEL;
  float4 xv = ((const float4*)xr)[t];
  float s  = xv.x + xv.y + xv.z + xv.w;
  float s2 = xv.x*xv.x + xv.y*xv.y + xv.z*xv.z + xv.w*xv.w;
  for (int d = 32; d > 0; d >>= 1) { s += __shfl_down(s, d); s2 += __shfl_down(s2, d); }
  int wid = t >> 6;
  if ((t & 63) == 0) { red[wid*2] = s; red[wid*2+1] = s2; }
  __syncthreads();
  if (t == 0) {
    float a = 0.f, b2 = 0.f;
    for (int i = 0; i < 4; ++i) { a += red[i*2]; b2 += red[i*2+1]; }
    red[8] = a; red[9] = b2;
  }
  __syncthreads();
  float mu  = red[8] * (1.0f / D_MODEL);
  float var = red[9] * (1.0f / D_MODEL) - mu*mu;
  float rstd = rsqrtf(var + 1e-12f);
  float4 gv = ((const float4*)g)[t];
  float4 bv = ((const float4*)be)[t];
  unsigned long long o =
      (unsigned long long)f2bf((xv.x - mu) * rstd * gv.x + bv.x)
    | ((unsigned long long)f2bf((xv.y - mu) * rstd * gv.y + bv.y) << 16)
    | ((unsigned long long)f2bf((xv.z - mu) * rstd * gv.z + bv.z) << 32)
    | ((unsigned long long)f2bf((xv.w - mu) * rstd * gv.w + bv.w) << 48);
  ((unsigned long long*)out)[(size_t)row * (D_MODEL/4) + t] = o;
}

// ---------------- Weight transpose fp32 [K,N] -> bf16 [N,K] ----------------
__global__ __launch_bounds__(256) void wt_kernel(const float* __restrict__ W,
                                                 u16* __restrict__ Wt, int K, int N) {
  __shared__ float tile[32][33];
  int n0 = blockIdx.x * 32, k0 = blockIdx.y * 32;
  int tx = threadIdx.x & 31, ty = threadIdx.x >> 5;   // ty: 0..7
  #pragma unroll
  for (int i = 0; i < 4; ++i) {
    int k = ty + i*8;
    tile[k][tx] = W[(size_t)(k0 + k) * N + n0 + tx];
  }
  __syncthreads();
  #pragma unroll
  for (int i = 0; i < 4; ++i) {
    int n = ty + i*8;
    Wt[(size_t)(n0 + n) * K + k0 + tx] = f2bf(tile[tx][n]);
  }
}

// ---------------- V transpose: [b,key,h,d] bf16 -> [b,h,d,key] bf16 --------
__global__ __launch_bounds__(256) void vtrans_kernel(const u16* __restrict__ vb,
                                                     u16* __restrict__ vt) {
  __shared__ __align__(16) u16 tile[64][80];
  int kb = blockIdx.x * 64;       // key block
  int bh = blockIdx.y;            // b*16+h
  int b = bh >> 4, h = bh & 15;
  int t = threadIdx.x;
  int key = t >> 2, dq = (t & 3) * 16;
  const u16* src = vb + (size_t)b*SEQ*D_MODEL + (size_t)(kb+key)*D_MODEL + h*HDIM + dq;
  *(bf16x8*)&tile[key][dq]     = *(const bf16x8*)(src);
  *(bf16x8*)&tile[key][dq + 8] = *(const bf16x8*)(src + 8);
  __syncthreads();
  int w = t >> 6, lane = t & 63;
  int kq = w * 16;
  u16 vals[16];
  #pragma unroll
  for (int e = 0; e < 16; ++e) vals[e] = tile[kq + e][lane];
  u16* dst = vt + (size_t)bh * HDIM * SEQ + (size_t)lane * SEQ + kb + kq;
  *(bf16x8*)dst       = *(const bf16x8*)&vals[0];
  *(bf16x8*)(dst + 8) = *(const bf16x8*)&vals[8];
}

// ---------------- GEMM 128x256, BK=32, tri-buffered, counted vmcnt ---------
// LDS 72 KiB -> 2 blocks/CU (16 waves). Per K-tile: 3 gl2lds (issue-early,
// 2 tiles ahead), 8 ds_read_b128, 16 MFMA, one barrier; vmcnt(3) keeps the
// t+2 prefetch in flight across the barrier (never drain to 0 mid-loop).
// Swizzle: col = (g ^ ((row>>1)&3))*8 both sides -> 2-way bank alias (free).
__device__ __forceinline__ float gelu_f(float v) {
  return 0.5f * v * (1.0f + erff(v * 0.70710678118654752f));
}

template<int EPI>
__global__ __launch_bounds__(512, 4) void gemm256(const u16* __restrict__ A,
                                                  const u16* __restrict__ Bt,
                                                  const float* __restrict__ bias,
                                                  const float* __restrict__ resid,
                                                  void* __restrict__ outp,
                                                  int M, int N, int K,
                                                  const float* __restrict__ bias2,
                                                  const float* __restrict__ bias3,
                                                  void* __restrict__ out2,
                                                  void* __restrict__ out3) {
  __shared__ __align__(16) u16 sA[3][128*32];   // 24 KiB
  __shared__ __align__(16) u16 sB[3][256*32];   // 48 KiB
  const int tid = threadIdx.x;
  const int lane = tid & 63, w = tid >> 6;
  const int r = lane & 15, kg = lane >> 4;
  const int rs = (r >> 1) & 3;                  // swizzle key for frag reads
  const int wr = w >> 2, wc = w & 3;

  // XCD-aware bijective swizzle (all launches have nwg % 8 == 0)
  const int gx = gridDim.x;
  const int nwg = gx * gridDim.y;
  const int orig = blockIdx.y * gx + blockIdx.x;
  const int lid = (orig & 7) * (nwg >> 3) + (orig >> 3);
  const int bm = lid / gx, bn = lid % gx;

  const int NT = K >> 5;

  // staging offsets: slot = u*512 + tid; row = slot>>2, g = slot&3
  // global source col pre-swizzled: (g ^ ((row>>1)&3))*8
  size_t offA, offB[2];
  {
    int row = tid >> 2, g = tid & 3;
    offA = (size_t)(bm*128 + row) * K + ((g ^ ((row >> 1) & 3)) * 8);
  }
  #pragma unroll
  for (int u = 0; u < 2; ++u) {
    int slot = u*512 + tid;
    int row = slot >> 2, g = slot & 3;
    offB[u] = (size_t)(bn*256 + row) * K + ((g ^ ((row >> 1) & 3)) * 8);
  }

  f32x4 acc[4][4];
  #pragma unroll
  for (int m = 0; m < 4; ++m)
    #pragma unroll
    for (int n = 0; n < 4; ++n) acc[m][n] = f32x4{0.f, 0.f, 0.f, 0.f};

  // per-section routing for EPI 3 (wave-uniform: bn 0-3 q, 4-7 k, 8-11 v)
  const float* bsel = bias;
  u16* osel = (u16*)outp;
  int bnl = bn;
  float qscale = 1.0f;
  if (EPI == 3) {
    int sec = bn >> 2;
    bsel = (sec == 0) ? bias : (sec == 1 ? bias2 : bias3);
    osel = (u16*)((sec == 0) ? outp : (sec == 1 ? out2 : out3));
    if (sec == 0) qscale = SCQ;
    bnl = bn & 3;
  }
  float bv4[4];
  #pragma unroll
  for (int n = 0; n < 4; ++n) bv4[n] = bsel[bnl*256 + wc*64 + n*16 + r];

  auto stage = [&](int bbuf, int t) {
    const size_t koff = (size_t)t * 32;
    gl2lds16(A  + offA    + koff, &sA[bbuf][tid*8]);
    gl2lds16(Bt + offB[0] + koff, &sB[bbuf][tid*8]);
    gl2lds16(Bt + offB[1] + koff, &sB[bbuf][(512+tid)*8]);
  };

  // ---- prologue: stage K-tiles 0 and 1 ----
  stage(0, 0);
  stage(1, 1);
  asm volatile("s_waitcnt vmcnt(3)" ::: "memory");
  __builtin_amdgcn_s_barrier();

  int buf = 0;
  for (int t = 0; t < NT; ++t) {
    const bool pre = (t + 2 < NT);
    int nb = buf + 2; if (nb >= 3) nb -= 3;

    if (pre) stage(nb, t + 2);           // issue-early, 2 tiles ahead

    bf16x8 af[4], bfr[4];
    #pragma unroll
    for (int m = 0; m < 4; ++m)
      af[m]  = *(const bf16x8*)&sA[buf][(wr*64 + m*16 + r)*32 + ((kg ^ rs) * 8)];
    #pragma unroll
    for (int n = 0; n < 4; ++n)
      bfr[n] = *(const bf16x8*)&sB[buf][(wc*64 + n*16 + r)*32 + ((kg ^ rs) * 8)];

    asm volatile("s_waitcnt lgkmcnt(0)" ::: "memory");
    __builtin_amdgcn_sched_barrier(0);
    __builtin_amdgcn_s_setprio(1);
    #pragma unroll
    for (int m = 0; m < 4; ++m)
      #pragma unroll
      for (int n = 0; n < 4; ++n)
        acc[m][n] = MFMA_BF16(af[m], bfr[n], acc[m][n]);
    __builtin_amdgcn_s_setprio(0);

    if (pre) asm volatile("s_waitcnt vmcnt(3)" ::: "memory");
    else     asm volatile("s_waitcnt vmcnt(0)" ::: "memory");
    __builtin_amdgcn_s_barrier();
    buf += 1; if (buf >= 3) buf -= 3;
  }

  // ---- epilogue ----
  const int orow = bm*128 + wr*64;
  const int ocol = (EPI == 3 ? bnl : bn)*256 + wc*64;
  const int ostride = (EPI == 3) ? 1024 : N;
  #pragma unroll
  for (int m = 0; m < 4; ++m) {
    #pragma unroll
    for (int n = 0; n < 4; ++n) {
      #pragma unroll
      for (int j = 0; j < 4; ++j) {
        int rr = orow + m*16 + kg*4 + j;
        int cc = ocol + n*16 + r;
        size_t idx = (size_t)rr * ostride + cc;
        float v = acc[m][n][j] + bv4[n];
        if (EPI == 0)       ((u16*)outp)[idx]   = f2bf(v);
        else if (EPI == 1)  ((float*)outp)[idx] = resid[idx] + v;
        else if (EPI == 2)  ((u16*)outp)[idx]   = f2bf(gelu_f(v));
        else                osel[idx]           = f2bf(v * qscale);
      }
    }
  }
}

// ---------------- Flash attention: 4 waves, 32 q/wave, 32x32 MFMA ---------
__global__ __launch_bounds__(256, 4) void attn_kernel(const u16* __restrict__ qb,
                                                      const u16* __restrict__ kb,
                                                      const u16* __restrict__ vt,
                                                      const int* __restrict__ mask,
                                                      u16* __restrict__ ob) {
  __shared__ __align__(16) u16 sK[2][64*64];   // 16 KiB
  __shared__ __align__(16) u16 sV[2][64*64];   // 16 KiB
  __shared__ float sAl[4][32];                 // per-wave alpha/rcp broadcast
  __shared__ unsigned char sOkPart[256];
  __shared__ unsigned sTileOk;
  const float THR2 = 11.541560327111708f;      // 8 * log2(e)
  int tid = threadIdx.x;
  int lane = tid & 63, w = tid >> 6;
  int l31 = lane & 31, hi = lane >> 5;
  int qt = blockIdx.x;            // 0..15, 128 q-rows per block
  int bh = blockIdx.y;
  int b = bh >> 4, h = bh & 15;
  size_t qkbase = (size_t)b * SEQ * D_MODEL + (size_t)h * HDIM;
  const u16* vtb = vt + (size_t)bh * HDIM * SEQ;
  const int* mrow = mask + b * SEQ;

  // ---- prologue: per-tile "fully unmasked" bitmap (32 tiles of 64 keys) ----
  {
    int ok = 1;
    #pragma unroll
    for (int e = 0; e < 8; ++e) ok &= (mrow[tid*8 + e] != 0);
    sOkPart[tid] = (unsigned char)ok;
  }
  __syncthreads();
  if (w == 0) {
    int a = 0;
    if (lane < 32) {
      a = 1;
      #pragma unroll
      for (int e = 0; e < 8; ++e) a &= sOkPart[lane*8 + e];
    }
    unsigned long long bits = __ballot(a != 0);
    if (lane == 0) sTileOk = (unsigned)(bits & 0xffffffffu);
  }
  __syncthreads();
  const unsigned tileOkBits = sTileOk;

  // Q fragments (B-operand): lane holds Q[q=l31][d = dstep*16 + hi*8 + e]
  const u16* qrow = qb + qkbase + (size_t)(qt*128 + w*32 + l31) * D_MODEL + hi*8;
  bf16x8 qf[4];
  #pragma unroll
  for (int dstep = 0; dstep < 4; ++dstep)
    qf[dstep] = *(const bf16x8*)(qrow + dstep*16);

  f32x16 oacc0, oacc1;           // O[q-rows][d = l31] and [d = 32+l31]
  #pragma unroll
  for (int e = 0; e < 16; ++e) { oacc0[e] = 0.f; oacc1[e] = 0.f; }
  float m_run = -1e30f;
  float lsum  = 0.f;

  // staging pointers: chunk c0 = w*64+lane, c1 = +256
  int ch0 = w*64 + lane, ch1 = ch0 + 256;
  int row0 = ch0 >> 3, col0 = ((ch0 & 7) ^ (row0 & 7)) * 8;
  int row1 = ch1 >> 3, col1 = ((ch1 & 7) ^ (row1 & 7)) * 8;
  const u16* kp0 = kb + qkbase + (size_t)row0 * D_MODEL + col0;
  const u16* kp1 = kb + qkbase + (size_t)row1 * D_MODEL + col1;
  const u16* vp0 = vtb + (size_t)row0 * SEQ + col0;
  const u16* vp1 = vtb + (size_t)row1 * SEQ + col1;

  const int NT = SEQ / 64;

  gl2lds16(kp0, &sK[0][ch0*8]);
  gl2lds16(kp1, &sK[0][ch1*8]);
  gl2lds16(vp0, &sV[0][ch0*8]);
  gl2lds16(vp1, &sV[0][ch1*8]);
  kp0 += 64*D_MODEL; kp1 += 64*D_MODEL; vp0 += 64; vp1 += 64;

  for (int kt = 0; kt < NT; ++kt) {
    int cur = kt & 1;
    int key0 = kt * 64;
    if (kt + 1 < NT) {
      gl2lds16(kp0, &sK[cur^1][ch0*8]);
      gl2lds16(kp1, &sK[cur^1][ch1*8]);
      gl2lds16(vp0, &sV[cur^1][ch0*8]);
      gl2lds16(vp1, &sV[cur^1][ch1*8]);
      kp0 += 64*D_MODEL; kp1 += 64*D_MODEL; vp0 += 64; vp1 += 64;
      asm volatile("s_waitcnt vmcnt(4)" ::: "memory");
    } else {
      asm volatile("s_waitcnt vmcnt(0)" ::: "memory");
    }
    __builtin_amdgcn_s_barrier();

    const u16* Kt = sK[cur];
    const u16* Vt = sV[cur];

    // ---- QK^T swapped: S[k][q], q = l31; s0 = keys 0..31, s1 = 32..63 ----
    f32x16 s0, s1;
    #pragma unroll
    for (int e = 0; e < 16; ++e) { s0[e] = 0.f; s1[e] = 0.f; }
    #pragma unroll
    for (int dstep = 0; dstep < 4; ++dstep) {
      int g = dstep*2 + hi;
      bf16x8 kf0 = *(const bf16x8*)&Kt[l31*64        + ((g ^ (l31 & 7)) * 8)];
      bf16x8 kf1 = *(const bf16x8*)&Kt[(32 + l31)*64 + ((g ^ ((32 + l31) & 7)) * 8)];
      s0 = MFMA32(kf0, qf[dstep], s0);
      s1 = MFMA32(kf1, qf[dstep], s1);
    }

    // ---- mask slow path (rare; block-uniform) ----
    if (!((tileOkBits >> kt) & 1u)) {
      #pragma unroll
      for (int reg = 0; reg < 16; ++reg) {
        int kr = (reg & 3) + 8*(reg >> 2) + 4*hi;
        if (!mrow[key0 + kr])      s0[reg] = -1e9f;
        if (!mrow[key0 + 32 + kr]) s1[reg] = -1e9f;
      }
    }

    // ---- per-q tile max (lane-local 31 fmax + one cross-half shfl) ----
    float tm = s0[0];
    #pragma unroll
    for (int e = 1; e < 16; ++e) tm = fmaxf(tm, s0[e]);
    #pragma unroll
    for (int e = 0; e < 16; ++e) tm = fmaxf(tm, s1[e]);
    tm = fmaxf(tm, __shfl_xor(tm, 32));

    // ---- defer-max rescale (rare) ----
    if (__any(tm > m_run + THR2)) {
      float mn = fmaxf(m_run, tm);
      float al = EXP2(m_run - mn);
      m_run = mn;
      lsum *= al;
      if (lane < 32) sAl[w][lane] = al;
      asm volatile("s_waitcnt lgkmcnt(0)" ::: "memory");
      #pragma unroll
      for (int reg = 0; reg < 16; ++reg) {
        float a2 = sAl[w][(reg & 3) + 8*(reg >> 2) + 4*hi];
        oacc0[reg] *= a2; oacc1[reg] *= a2;
      }
    }

    // ---- P = exp2(s - m), lane-local row-sum ----
    #pragma unroll
    for (int e = 0; e < 16; ++e) {
      s0[e] = EXP2(s0[e] - m_run); lsum += s0[e];
      s1[e] = EXP2(s1[e] - m_run); lsum += s1[e];
    }

    // ---- pack P to bf16 A-frags in-register (cvt_pk + permlane32_swap) ----
    unsigned wa, wb, wc, wd, we, wf, wg, wh;
#define CVTPK(dst, lo_, hi_) asm("v_cvt_pk_bf16_f32 %0, %1, %2" : "=v"(dst) : "v"(lo_), "v"(hi_))
    CVTPK(wa, s0[0],  s0[1]);  CVTPK(wb, s0[2],  s0[3]);
    CVTPK(wc, s0[4],  s0[5]);  CVTPK(wd, s0[6],  s0[7]);
    CVTPK(we, s0[8],  s0[9]);  CVTPK(wf, s0[10], s0[11]);
    CVTPK(wg, s0[12], s0[13]); CVTPK(wh, s0[14], s0[15]);
    asm volatile("v_permlane32_swap_b32 %0, %1" : "+v"(wc), "+v"(wa));
    asm volatile("v_permlane32_swap_b32 %0, %1" : "+v"(wd), "+v"(wb));
    asm volatile("v_permlane32_swap_b32 %0, %1" : "+v"(wg), "+v"(we));
    asm volatile("v_permlane32_swap_b32 %0, %1" : "+v"(wh), "+v"(wf));
    bf16x8 pa0 = mk8(wa, wb, wc, wd);   // keys 0..15
    bf16x8 pa1 = mk8(we, wf, wg, wh);   // keys 16..31
    CVTPK(wa, s1[0],  s1[1]);  CVTPK(wb, s1[2],  s1[3]);
    CVTPK(wc, s1[4],  s1[5]);  CVTPK(wd, s1[6],  s1[7]);
    CVTPK(we, s1[8],  s1[9]);  CVTPK(wf, s1[10], s1[11]);
    CVTPK(wg, s1[12], s1[13]); CVTPK(wh, s1[14], s1[15]);
    asm volatile("v_permlane32_swap_b32 %0, %1" : "+v"(wc), "+v"(wa));
    asm volatile("v_permlane32_swap_b32 %0, %1" : "+v"(wd), "+v"(wb));
    asm volatile("v_permlane32_swap_b32 %0, %1" : "+v"(wg), "+v"(we));
    asm volatile("v_permlane32_swap_b32 %0, %1" : "+v"(wh), "+v"(wf));
    bf16x8 pa2 = mk8(wa, wb, wc, wd);   // keys 32..47
    bf16x8 pa3 = mk8(we, wf, wg, wh);   // keys 48..63
#undef CVTPK

    // ---- PV: O[q][d] += P[q][k] V[k][d]; B-frag from vt rows (d-major) ----
    int r0 = l31, r1 = 32 + l31;
    #pragma unroll
    for (int kstep = 0; kstep < 4; ++kstep) {
      int g = kstep*2 + hi;
      bf16x8 vf0 = *(const bf16x8*)&Vt[r0*64 + ((g ^ (r0 & 7)) * 8)];
      bf16x8 vf1 = *(const bf16x8*)&Vt[r1*64 + ((g ^ (r1 & 7)) * 8)];
      bf16x8 pk = (kstep == 0) ? pa0 : (kstep == 1) ? pa1 : (kstep == 2) ? pa2 : pa3;
      oacc0 = MFMA32(pk, vf0, oacc0);
      oacc1 = MFMA32(pk, vf1, oacc1);
    }
    __builtin_amdgcn_s_barrier();
  }

  // ---- finalize: per-q 1/l broadcast, normalize, store ----
  float lsumT = lsum + __shfl_xor(lsum, 32);
  if (lane < 32) sAl[w][lane] = 1.0f / lsumT;
  asm volatile("s_waitcnt lgkmcnt(0)" ::: "memory");
  #pragma unroll
  for (int reg = 0; reg < 16; ++reg) {
    int qr = (reg & 3) + 8*(reg >> 2) + 4*hi;
    float rc = sAl[w][qr];
    int qg = qt*128 + w*32 + qr;
    size_t base2 = (size_t)(b*SEQ + qg) * D_MODEL + h*HDIM + l31;
    ob[base2]      = f2bf(oacc0[reg] * rc);
    ob[base2 + 32] = f2bf(oacc1[reg] * rc);
  }
}

// ---------------- launch ----------------
extern "C" void kernel_launch(void* const* d_in, const int* in_sizes, int n_in,
                              void* d_out, int out_size, void* d_ws, size_t ws_size,
                              hipStream_t stream) {
  const float* x   = (const float*)d_in[0];
  const int*  mask = (const int*)d_in[1];
  const float* Wq = (const float*)d_in[2];  const float* bq = (const float*)d_in[3];
  const float* Wk = (const float*)d_in[4];  const float* bk = (const float*)d_in[5];
  const float* Wv = (const float*)d_in[6];  const float* bv = (const float*)d_in[7];
  const float* Wo = (const float*)d_in[8];  const float* bo = (const float*)d_in[9];
  const float* W1 = (const float*)d_in[10]; const float* b1 = (const float*)d_in[11];
  const float* W2 = (const float*)d_in[12]; const float* b2 = (const float*)d_in[13];
  const float* g1 = (const float*)d_in[14]; const float* be1 = (const float*)d_in[15];
  const float* g2 = (const float*)d_in[16]; const float* be2 = (const float*)d_in[17];

  const size_t MB = 1u << 20;
  char* ws = (char*)d_ws;
  u16*  hln  = (u16*)(ws);              // 16MB  (LN1 out; later reused: vt, then LN2 out)
  u16*  vt   = (u16*)(ws);              // 16MB  V^T [b,h,d,key] — overwrites hln after QKV
  u16*  qb   = (u16*)(ws + 16*MB);      // 16MB
  u16*  kb   = (u16*)(ws + 32*MB);      // 16MB
  u16*  vb   = (u16*)(ws + 48*MB);      // 16MB
  u16*  attn = (u16*)(ws + 64*MB);      // 16MB
  u16*  ff1  = (u16*)(ws + 16*MB);      // 64MB, reuses q/k/v/attn region
  float* x2  = (float*)(ws + 80*MB);    // 32MB
  u16*  WqkvT= (u16*)(ws + 112*MB);     // 6MB contiguous: [3072][1024] (q|k|v)
  u16*  WqT  = WqkvT;
  u16*  WkT  = (u16*)(ws + 114*MB);
  u16*  WvT  = (u16*)(ws + 116*MB);
  u16*  WoT  = (u16*)(ws + 118*MB);
  u16*  W1T  = (u16*)(ws + 120*MB);     // [4096,1024] 8MB
  u16*  W2T  = (u16*)(ws + 128*MB);     // [1024,4096] 8MB

  dim3 tb(256);
  wt_kernel<<<dim3(1024/32, 1024/32), tb, 0, stream>>>(Wq, WqT, 1024, 1024);
  wt_kernel<<<dim3(1024/32, 1024/32), tb, 0, stream>>>(Wk, WkT, 1024, 1024);
  wt_kernel<<<dim3(1024/32, 1024/32), tb, 0, stream>>>(Wv, WvT, 1024, 1024);
  wt_kernel<<<dim3(1024/32, 1024/32), tb, 0, stream>>>(Wo, WoT, 1024, 1024);
  wt_kernel<<<dim3(4096/32, 1024/32), tb, 0, stream>>>(W1, W1T, 1024, 4096);
  wt_kernel<<<dim3(1024/32, 4096/32), tb, 0, stream>>>(W2, W2T, 4096, 1024);

  ln_kernel<<<ROWS, tb, 0, stream>>>(x, g1, be1, hln);

  dim3 gb(512);
  // fused QKV: one GEMM over [3072][1024] weights, routed epilogue (q pre-scaled)
  gemm256<3><<<dim3(3072/256, ROWS/128), gb, 0, stream>>>(hln, WqkvT, bq, nullptr, qb,
                                                          ROWS, 3072, 1024,
                                                          bk, bv, kb, vb);

  vtrans_kernel<<<dim3(SEQ/64, BATCH*NHEAD), tb, 0, stream>>>(vb, vt);

  attn_kernel<<<dim3(SEQ/128, BATCH*NHEAD), tb, 0, stream>>>(qb, kb, vt, mask, attn);

  gemm256<1><<<dim3(1024/256, ROWS/128), gb, 0, stream>>>(attn, WoT, bo, x, x2,
                                                          ROWS, 1024, 1024,
                                                          nullptr, nullptr, nullptr, nullptr);

  ln_kernel<<<ROWS, tb, 0, stream>>>(x2, g2, be2, hln);

  gemm256<2><<<dim3(4096/256, ROWS/128), gb, 0, stream>>>(hln, W1T, b1, nullptr, ff1,
                                                          ROWS, 4096, 1024,
                                                          nullptr, nullptr, nullptr, nullptr);

  gemm256<1><<<dim3(1024/256, ROWS/128), gb, 0, stream>>>(ff1, W2T, b2, x2, (float*)d_out,
                                                          ROWS, 1024, 4096,
                                                          nullptr, nullptr, nullptr, nullptr);
}

// Round 10
// 437.570 us; speedup vs baseline: 1.0157x; 1.0157x over previous
//
#include <hip/hip_runtime.h>
#include <stdint.h>

#define D_MODEL 1024
#define NHEAD   16
#define HDIM    64
#define FFDIM   4096
#define BATCH   4
#define SEQ     2048
#define ROWS    (BATCH*SEQ)   // 8192

typedef unsigned short u16;
typedef __bf16 bf16_t;
typedef bf16_t bf16x8 __attribute__((ext_vector_type(8)));
typedef float  f32x4  __attribute__((ext_vector_type(4)));
typedef float  f32x16 __attribute__((ext_vector_type(16)));

#define SCQ 0.18033688011112042f   // 0.125 * log2(e) — folded into Q at QKV epilogue

__device__ __forceinline__ u16 f2bf(float f) {
  union { float f; unsigned u; } v; v.f = f;
  unsigned r = v.u + 0x7fffu + ((v.u >> 16) & 1u);
  return (u16)(r >> 16);
}

__device__ __forceinline__ void gl2lds16(const void* g, void* l) {
  __builtin_amdgcn_global_load_lds((const __attribute__((address_space(1))) void*)g,
                                   (__attribute__((address_space(3))) void*)l, 16, 0, 0);
}

#define MFMA_BF16(a, b, c) __builtin_amdgcn_mfma_f32_16x16x32_bf16((a), (b), (c), 0, 0, 0)
#define MFMA32(a, b, c)    __builtin_amdgcn_mfma_f32_32x32x16_bf16((a), (b), (c), 0, 0, 0)
#define EXP2(x) __builtin_amdgcn_exp2f(x)

__device__ __forceinline__ bf16x8 mk8(unsigned a, unsigned b, unsigned c, unsigned d) {
  union { unsigned u[4]; bf16x8 v; } t;
  t.u[0] = a; t.u[1] = b; t.u[2] = c; t.u[3] = d;
  return t.v;
}

// ---------------- LayerNorm (fp32 in -> bf16 out) ----------------
__global__ __launch_bounds__(256) void ln_kernel(const float* __restrict__ x,
                                                 const float* __restrict__ g,
                                                 const float* __restrict__ be,
                                                 u16* __restrict__ out) {
  __shared__ float red[10];
  int row = blockIdx.x;
  int t = threadIdx.x;
  const float* xr = x + (size_t)row * D_MODEL;
  float4 xv = ((const float4*)xr)[t];
  float s  = xv.x + xv.y + xv.z + xv.w;
  float s2 = xv.x*xv.x + xv.y*xv.y + xv.z*xv.z + xv.w*xv.w;
  for (int d = 32; d > 0; d >>= 1) { s += __shfl_down(s, d); s2 += __shfl_down(s2, d); }
  int wid = t >> 6;
  if ((t & 63) == 0) { red[wid*2] = s; red[wid*2+1] = s2; }
  __syncthreads();
  if (t == 0) {
    float a = 0.f, b2 = 0.f;
    for (int i = 0; i < 4; ++i) { a += red[i*2]; b2 += red[i*2+1]; }
    red[8] = a; red[9] = b2;
  }
  __syncthreads();
  float mu  = red[8] * (1.0f / D_MODEL);
  float var = red[9] * (1.0f / D_MODEL) - mu*mu;
  float rstd = rsqrtf(var + 1e-12f);
  float4 gv = ((const float4*)g)[t];
  float4 bv = ((const float4*)be)[t];
  unsigned long long o =
      (unsigned long long)f2bf((xv.x - mu) * rstd * gv.x + bv.x)
    | ((unsigned long long)f2bf((xv.y - mu) * rstd * gv.y + bv.y) << 16)
    | ((unsigned long long)f2bf((xv.z - mu) * rstd * gv.z + bv.z) << 32)
    | ((unsigned long long)f2bf((xv.w - mu) * rstd * gv.w + bv.w) << 48);
  ((unsigned long long*)out)[(size_t)row * (D_MODEL/4) + t] = o;
}

// ---------------- Weight transpose fp32 [K,N] -> bf16 [N,K] ----------------
__global__ __launch_bounds__(256) void wt_kernel(const float* __restrict__ W,
                                                 u16* __restrict__ Wt, int K, int N) {
  __shared__ float tile[32][33];
  int n0 = blockIdx.x * 32, k0 = blockIdx.y * 32;
  int tx = threadIdx.x & 31, ty = threadIdx.x >> 5;   // ty: 0..7
  #pragma unroll
  for (int i = 0; i < 4; ++i) {
    int k = ty + i*8;
    tile[k][tx] = W[(size_t)(k0 + k) * N + n0 + tx];
  }
  __syncthreads();
  #pragma unroll
  for (int i = 0; i < 4; ++i) {
    int n = ty + i*8;
    Wt[(size_t)(n0 + n) * K + k0 + tx] = f2bf(tile[tx][n]);
  }
}

// ---------------- V transpose: [b,key,h,d] bf16 -> [b,h,d,key] bf16 --------
__global__ __launch_bounds__(256) void vtrans_kernel(const u16* __restrict__ vb,
                                                     u16* __restrict__ vt) {
  __shared__ __align__(16) u16 tile[64][80];
  int kb = blockIdx.x * 64;       // key block
  int bh = blockIdx.y;            // b*16+h
  int b = bh >> 4, h = bh & 15;
  int t = threadIdx.x;
  int key = t >> 2, dq = (t & 3) * 16;
  const u16* src = vb + (size_t)b*SEQ*D_MODEL + (size_t)(kb+key)*D_MODEL + h*HDIM + dq;
  *(bf16x8*)&tile[key][dq]     = *(const bf16x8*)(src);
  *(bf16x8*)&tile[key][dq + 8] = *(const bf16x8*)(src + 8);
  __syncthreads();
  int w = t >> 6, lane = t & 63;
  int kq = w * 16;
  u16 vals[16];
  #pragma unroll
  for (int e = 0; e < 16; ++e) vals[e] = tile[kq + e][lane];
  u16* dst = vt + (size_t)bh * HDIM * SEQ + (size_t)lane * SEQ + kb + kq;
  *(bf16x8*)dst       = *(const bf16x8*)&vals[0];
  *(bf16x8*)(dst + 8) = *(const bf16x8*)&vals[8];
}

// ---------------- GEMM 128x128, BK=32 — m97 structure (measured 912 TF) ----
// Single-buffer 16 KB LDS, 2 barriers/K-step, 4 gl2lds/thread, 16 MFMA/wave.
// Latency hidden by ~3 co-resident blocks/CU (wave-level overlap, m114).
// LDS swizzle: col group g' = g ^ (row&3), both sides (free 2-way alias).
// EPI 0: bf16 = C+bias   1: f32 = resid+C+bias   2: bf16 = gelu(C+bias)
// EPI 3: QKV fused (N=3072): route by bn>>3, q pre-scaled by SCQ.
__device__ __forceinline__ float gelu_f(float v) {
  return 0.5f * v * (1.0f + erff(v * 0.70710678118654752f));
}

template<int EPI>
__global__ __launch_bounds__(256) void gemm_bt(const u16* __restrict__ A,
                                               const u16* __restrict__ Bt,
                                               const float* __restrict__ bias,
                                               const float* __restrict__ resid,
                                               void* __restrict__ outp,
                                               int M, int N, int K,
                                               const float* __restrict__ bias2,
                                               const float* __restrict__ bias3,
                                               void* __restrict__ out2,
                                               void* __restrict__ out3) {
  __shared__ __align__(16) u16 sA[128*32];   // 8 KiB
  __shared__ __align__(16) u16 sB[128*32];   // 8 KiB
  const int tid = threadIdx.x;
  const int lane = tid & 63, w = tid >> 6;
  const int r = lane & 15, kg = lane >> 4;
  const int ks = kg ^ (r & 3);               // lane-constant frag swizzle key
  const int wr = w >> 1, wc = w & 1;

  // XCD-aware bijective swizzle (all launches have nwg % 8 == 0)
  const int gx = gridDim.x;
  const int nwg = gx * gridDim.y;
  const int orig = blockIdx.y * gx + blockIdx.x;
  const int lid = (orig & 7) * (nwg >> 3) + (orig >> 3);
  const int bm = lid / gx, bn = lid % gx;

  // staging: slot u*256+tid -> row = slot>>2 (0..127), g = slot&3
  // global col pre-swizzled: (g ^ (row&3))*8 ; LDS dest linear slot*8 elems
  int row0 = tid >> 2, g0 = tid & 3;
  int row1 = 64 + row0;
  int c0 = (g0 ^ (row0 & 3)) * 8;
  int c1 = (g0 ^ (row1 & 3)) * 8;            // row1&3 == row0&3, same value
  const u16* Ag0 = A  + (size_t)(bm*128 + row0) * K + c0;
  const u16* Ag1 = A  + (size_t)(bm*128 + row1) * K + c1;
  const u16* Bg0 = Bt + (size_t)(bn*128 + row0) * K + c0;
  const u16* Bg1 = Bt + (size_t)(bn*128 + row1) * K + c1;
  u16* lA0 = sA + tid*8;
  u16* lA1 = sA + (256 + tid)*8;
  u16* lB0 = sB + tid*8;
  u16* lB1 = sB + (256 + tid)*8;

  f32x4 acc[4][4];
  #pragma unroll
  for (int m = 0; m < 4; ++m)
    #pragma unroll
    for (int n = 0; n < 4; ++n) acc[m][n] = f32x4{0.f, 0.f, 0.f, 0.f};

  // per-section routing for EPI 3 (wave-uniform: bn 0-7 q, 8-15 k, 16-23 v)
  const float* bsel = bias;
  u16* osel = (u16*)outp;
  int bnl = bn;
  float qscale = 1.0f;
  if (EPI == 3) {
    int sec = bn >> 3;
    bsel = (sec == 0) ? bias : (sec == 1 ? bias2 : bias3);
    osel = (u16*)((sec == 0) ? outp : (sec == 1 ? out2 : out3));
    if (sec == 0) qscale = SCQ;
    bnl = bn & 7;
  }
  float bv4[4];
  #pragma unroll
  for (int n = 0; n < 4; ++n) bv4[n] = bsel[bnl*128 + wc*64 + n*16 + r];

  for (int k0 = 0; k0 < K; k0 += 32) {
    gl2lds16(Ag0 + k0, lA0);
    gl2lds16(Ag1 + k0, lA1);
    gl2lds16(Bg0 + k0, lB0);
    gl2lds16(Bg1 + k0, lB1);
    __syncthreads();
    bf16x8 af[4], bfr[4];
    #pragma unroll
    for (int m = 0; m < 4; ++m) af[m]  = *(const bf16x8*)&sA[(wr*64 + m*16 + r)*32 + ks*8];
    #pragma unroll
    for (int n = 0; n < 4; ++n) bfr[n] = *(const bf16x8*)&sB[(wc*64 + n*16 + r)*32 + ks*8];
    __builtin_amdgcn_s_setprio(1);
    #pragma unroll
    for (int m = 0; m < 4; ++m)
      #pragma unroll
      for (int n = 0; n < 4; ++n)
        acc[m][n] = MFMA_BF16(af[m], bfr[n], acc[m][n]);
    __builtin_amdgcn_s_setprio(0);
    __syncthreads();
  }

  // ---- epilogue ----
  const int orow = bm*128 + wr*64;
  const int ocol = (EPI == 3 ? bnl : bn)*128 + wc*64;
  const int ostride = (EPI == 3) ? 1024 : N;
  #pragma unroll
  for (int m = 0; m < 4; ++m) {
    #pragma unroll
    for (int n = 0; n < 4; ++n) {
      #pragma unroll
      for (int j = 0; j < 4; ++j) {
        int rr = orow + m*16 + kg*4 + j;
        int cc = ocol + n*16 + r;
        size_t idx = (size_t)rr * ostride + cc;
        float v = acc[m][n][j] + bv4[n];
        if (EPI == 0)       ((u16*)outp)[idx]   = f2bf(v);
        else if (EPI == 1)  ((float*)outp)[idx] = resid[idx] + v;
        else if (EPI == 2)  ((u16*)outp)[idx]   = f2bf(gelu_f(v));
        else                osel[idx]           = f2bf(v * qscale);
      }
    }
  }
}

// ---------------- Flash attention: 4 waves, 32 q/wave, 32x32 MFMA ---------
__global__ __launch_bounds__(256, 4) void attn_kernel(const u16* __restrict__ qb,
                                                      const u16* __restrict__ kb,
                                                      const u16* __restrict__ vt,
                                                      const int* __restrict__ mask,
                                                      u16* __restrict__ ob) {
  __shared__ __align__(16) u16 sK[2][64*64];   // 16 KiB
  __shared__ __align__(16) u16 sV[2][64*64];   // 16 KiB
  __shared__ float sAl[4][32];                 // per-wave alpha/rcp broadcast
  __shared__ unsigned char sOkPart[256];
  __shared__ unsigned sTileOk;
  const float THR2 = 11.541560327111708f;      // 8 * log2(e)
  int tid = threadIdx.x;
  int lane = tid & 63, w = tid >> 6;
  int l31 = lane & 31, hi = lane >> 5;
  int qt = blockIdx.x;            // 0..15, 128 q-rows per block
  int bh = blockIdx.y;
  int b = bh >> 4, h = bh & 15;
  size_t qkbase = (size_t)b * SEQ * D_MODEL + (size_t)h * HDIM;
  const u16* vtb = vt + (size_t)bh * HDIM * SEQ;
  const int* mrow = mask + b * SEQ;

  // ---- prologue: per-tile "fully unmasked" bitmap (32 tiles of 64 keys) ----
  {
    int ok = 1;
    #pragma unroll
    for (int e = 0; e < 8; ++e) ok &= (mrow[tid*8 + e] != 0);
    sOkPart[tid] = (unsigned char)ok;
  }
  __syncthreads();
  if (w == 0) {
    int a = 0;
    if (lane < 32) {
      a = 1;
      #pragma unroll
      for (int e = 0; e < 8; ++e) a &= sOkPart[lane*8 + e];
    }
    unsigned long long bits = __ballot(a != 0);
    if (lane == 0) sTileOk = (unsigned)(bits & 0xffffffffu);
  }
  __syncthreads();
  const unsigned tileOkBits = sTileOk;

  // Q fragments (B-operand): lane holds Q[q=l31][d = dstep*16 + hi*8 + e]
  const u16* qrow = qb + qkbase + (size_t)(qt*128 + w*32 + l31) * D_MODEL + hi*8;
  bf16x8 qf[4];
  #pragma unroll
  for (int dstep = 0; dstep < 4; ++dstep)
    qf[dstep] = *(const bf16x8*)(qrow + dstep*16);

  f32x16 oacc0, oacc1;           // O[q-rows][d = l31] and [d = 32+l31]
  #pragma unroll
  for (int e = 0; e < 16; ++e) { oacc0[e] = 0.f; oacc1[e] = 0.f; }
  float m_run = -1e30f;
  float lsum  = 0.f;

  // staging pointers: chunk c0 = w*64+lane, c1 = +256
  int ch0 = w*64 + lane, ch1 = ch0 + 256;
  int row0 = ch0 >> 3, col0 = ((ch0 & 7) ^ (row0 & 7)) * 8;
  int row1 = ch1 >> 3, col1 = ((ch1 & 7) ^ (row1 & 7)) * 8;
  const u16* kp0 = kb + qkbase + (size_t)row0 * D_MODEL + col0;
  const u16* kp1 = kb + qkbase + (size_t)row1 * D_MODEL + col1;
  const u16* vp0 = vtb + (size_t)row0 * SEQ + col0;
  const u16* vp1 = vtb + (size_t)row1 * SEQ + col1;

  const int NT = SEQ / 64;

  gl2lds16(kp0, &sK[0][ch0*8]);
  gl2lds16(kp1, &sK[0][ch1*8]);
  gl2lds16(vp0, &sV[0][ch0*8]);
  gl2lds16(vp1, &sV[0][ch1*8]);
  kp0 += 64*D_MODEL; kp1 += 64*D_MODEL; vp0 += 64; vp1 += 64;

  for (int kt = 0; kt < NT; ++kt) {
    int cur = kt & 1;
    int key0 = kt * 64;
    if (kt + 1 < NT) {
      gl2lds16(kp0, &sK[cur^1][ch0*8]);
      gl2lds16(kp1, &sK[cur^1][ch1*8]);
      gl2lds16(vp0, &sV[cur^1][ch0*8]);
      gl2lds16(vp1, &sV[cur^1][ch1*8]);
      kp0 += 64*D_MODEL; kp1 += 64*D_MODEL; vp0 += 64; vp1 += 64;
      asm volatile("s_waitcnt vmcnt(4)" ::: "memory");
    } else {
      asm volatile("s_waitcnt vmcnt(0)" ::: "memory");
    }
    __builtin_amdgcn_s_barrier();

    const u16* Kt = sK[cur];
    const u16* Vt = sV[cur];

    // ---- QK^T swapped: S[k][q], q = l31; s0 = keys 0..31, s1 = 32..63 ----
    f32x16 s0, s1;
    #pragma unroll
    for (int e = 0; e < 16; ++e) { s0[e] = 0.f; s1[e] = 0.f; }
    #pragma unroll
    for (int dstep = 0; dstep < 4; ++dstep) {
      int g = dstep*2 + hi;
      bf16x8 kf0 = *(const bf16x8*)&Kt[l31*64        + ((g ^ (l31 & 7)) * 8)];
      bf16x8 kf1 = *(const bf16x8*)&Kt[(32 + l31)*64 + ((g ^ ((32 + l31) & 7)) * 8)];
      s0 = MFMA32(kf0, qf[dstep], s0);
      s1 = MFMA32(kf1, qf[dstep], s1);
    }

    // ---- mask slow path (rare; block-uniform) ----
    if (!((tileOkBits >> kt) & 1u)) {
      #pragma unroll
      for (int reg = 0; reg < 16; ++reg) {
        int kr = (reg & 3) + 8*(reg >> 2) + 4*hi;
        if (!mrow[key0 + kr])      s0[reg] = -1e9f;
        if (!mrow[key0 + 32 + kr]) s1[reg] = -1e9f;
      }
    }

    // ---- per-q tile max (lane-local 31 fmax + one cross-half shfl) ----
    float tm = s0[0];
    #pragma unroll
    for (int e = 1; e < 16; ++e) tm = fmaxf(tm, s0[e]);
    #pragma unroll
    for (int e = 0; e < 16; ++e) tm = fmaxf(tm, s1[e]);
    tm = fmaxf(tm, __shfl_xor(tm, 32));

    // ---- defer-max rescale (rare) ----
    if (__any(tm > m_run + THR2)) {
      float mn = fmaxf(m_run, tm);
      float al = EXP2(m_run - mn);
      m_run = mn;
      lsum *= al;
      if (lane < 32) sAl[w][lane] = al;
      asm volatile("s_waitcnt lgkmcnt(0)" ::: "memory");
      #pragma unroll
      for (int reg = 0; reg < 16; ++reg) {
        float a2 = sAl[w][(reg & 3) + 8*(reg >> 2) + 4*hi];
        oacc0[reg] *= a2; oacc1[reg] *= a2;
      }
    }

    // ---- P = exp2(s - m), lane-local row-sum ----
    #pragma unroll
    for (int e = 0; e < 16; ++e) {
      s0[e] = EXP2(s0[e] - m_run); lsum += s0[e];
      s1[e] = EXP2(s1[e] - m_run); lsum += s1[e];
    }

    // ---- pack P to bf16 A-frags in-register (cvt_pk + permlane32_swap) ----
    unsigned wa, wb, wc, wd, we, wf, wg, wh;
#define CVTPK(dst, lo_, hi_) asm("v_cvt_pk_bf16_f32 %0, %1, %2" : "=v"(dst) : "v"(lo_), "v"(hi_))
    CVTPK(wa, s0[0],  s0[1]);  CVTPK(wb, s0[2],  s0[3]);
    CVTPK(wc, s0[4],  s0[5]);  CVTPK(wd, s0[6],  s0[7]);
    CVTPK(we, s0[8],  s0[9]);  CVTPK(wf, s0[10], s0[11]);
    CVTPK(wg, s0[12], s0[13]); CVTPK(wh, s0[14], s0[15]);
    asm volatile("v_permlane32_swap_b32 %0, %1" : "+v"(wc), "+v"(wa));
    asm volatile("v_permlane32_swap_b32 %0, %1" : "+v"(wd), "+v"(wb));
    asm volatile("v_permlane32_swap_b32 %0, %1" : "+v"(wg), "+v"(we));
    asm volatile("v_permlane32_swap_b32 %0, %1" : "+v"(wh), "+v"(wf));
    bf16x8 pa0 = mk8(wa, wb, wc, wd);   // keys 0..15
    bf16x8 pa1 = mk8(we, wf, wg, wh);   // keys 16..31
    CVTPK(wa, s1[0],  s1[1]);  CVTPK(wb, s1[2],  s1[3]);
    CVTPK(wc, s1[4],  s1[5]);  CVTPK(wd, s1[6],  s1[7]);
    CVTPK(we, s1[8],  s1[9]);  CVTPK(wf, s1[10], s1[11]);
    CVTPK(wg, s1[12], s1[13]); CVTPK(wh, s1[14], s1[15]);
    asm volatile("v_permlane32_swap_b32 %0, %1" : "+v"(wc), "+v"(wa));
    asm volatile("v_permlane32_swap_b32 %0, %1" : "+v"(wd), "+v"(wb));
    asm volatile("v_permlane32_swap_b32 %0, %1" : "+v"(wg), "+v"(we));
    asm volatile("v_permlane32_swap_b32 %0, %1" : "+v"(wh), "+v"(wf));
    bf16x8 pa2 = mk8(wa, wb, wc, wd);   // keys 32..47
    bf16x8 pa3 = mk8(we, wf, wg, wh);   // keys 48..63
#undef CVTPK

    // ---- PV: O[q][d] += P[q][k] V[k][d]; B-frag from vt rows (d-major) ----
    int r0 = l31, r1 = 32 + l31;
    #pragma unroll
    for (int kstep = 0; kstep < 4; ++kstep) {
      int g = kstep*2 + hi;
      bf16x8 vf0 = *(const bf16x8*)&Vt[r0*64 + ((g ^ (r0 & 7)) * 8)];
      bf16x8 vf1 = *(const bf16x8*)&Vt[r1*64 + ((g ^ (r1 & 7)) * 8)];
      bf16x8 pk = (kstep == 0) ? pa0 : (kstep == 1) ? pa1 : (kstep == 2) ? pa2 : pa3;
      oacc0 = MFMA32(pk, vf0, oacc0);
      oacc1 = MFMA32(pk, vf1, oacc1);
    }
    __builtin_amdgcn_s_barrier();
  }

  // ---- finalize: per-q 1/l broadcast, normalize, store ----
  float lsumT = lsum + __shfl_xor(lsum, 32);
  if (lane < 32) sAl[w][lane] = 1.0f / lsumT;
  asm volatile("s_waitcnt lgkmcnt(0)" ::: "memory");
  #pragma unroll
  for (int reg = 0; reg < 16; ++reg) {
    int qr = (reg & 3) + 8*(reg >> 2) + 4*hi;
    float rc = sAl[w][qr];
    int qg = qt*128 + w*32 + qr;
    size_t base2 = (size_t)(b*SEQ + qg) * D_MODEL + h*HDIM + l31;
    ob[base2]      = f2bf(oacc0[reg] * rc);
    ob[base2 + 32] = f2bf(oacc1[reg] * rc);
  }
}

// ---------------- launch ----------------
extern "C" void kernel_launch(void* const* d_in, const int* in_sizes, int n_in,
                              void* d_out, int out_size, void* d_ws, size_t ws_size,
                              hipStream_t stream) {
  const float* x   = (const float*)d_in[0];
  const int*  mask = (const int*)d_in[1];
  const float* Wq = (const float*)d_in[2];  const float* bq = (const float*)d_in[3];
  const float* Wk = (const float*)d_in[4];  const float* bk = (const float*)d_in[5];
  const float* Wv = (const float*)d_in[6];  const float* bv = (const float*)d_in[7];
  const float* Wo = (const float*)d_in[8];  const float* bo = (const float*)d_in[9];
  const float* W1 = (const float*)d_in[10]; const float* b1 = (const float*)d_in[11];
  const float* W2 = (const float*)d_in[12]; const float* b2 = (const float*)d_in[13];
  const float* g1 = (const float*)d_in[14]; const float* be1 = (const float*)d_in[15];
  const float* g2 = (const float*)d_in[16]; const float* be2 = (const float*)d_in[17];

  const size_t MB = 1u << 20;
  char* ws = (char*)d_ws;
  u16*  hln  = (u16*)(ws);              // 16MB  (LN1 out; later reused: vt, then LN2 out)
  u16*  vt   = (u16*)(ws);              // 16MB  V^T [b,h,d,key] — overwrites hln after QKV
  u16*  qb   = (u16*)(ws + 16*MB);      // 16MB
  u16*  kb   = (u16*)(ws + 32*MB);      // 16MB
  u16*  vb   = (u16*)(ws + 48*MB);      // 16MB
  u16*  attn = (u16*)(ws + 64*MB);      // 16MB
  u16*  ff1  = (u16*)(ws + 16*MB);      // 64MB, reuses q/k/v/attn region
  float* x2  = (float*)(ws + 80*MB);    // 32MB
  u16*  WqkvT= (u16*)(ws + 112*MB);     // 6MB contiguous: [3072][1024] (q|k|v)
  u16*  WqT  = WqkvT;
  u16*  WkT  = (u16*)(ws + 114*MB);
  u16*  WvT  = (u16*)(ws + 116*MB);
  u16*  WoT  = (u16*)(ws + 118*MB);
  u16*  W1T  = (u16*)(ws + 120*MB);     // [4096,1024] 8MB
  u16*  W2T  = (u16*)(ws + 128*MB);     // [1024,4096] 8MB

  dim3 tb(256);
  wt_kernel<<<dim3(1024/32, 1024/32), tb, 0, stream>>>(Wq, WqT, 1024, 1024);
  wt_kernel<<<dim3(1024/32, 1024/32), tb, 0, stream>>>(Wk, WkT, 1024, 1024);
  wt_kernel<<<dim3(1024/32, 1024/32), tb, 0, stream>>>(Wv, WvT, 1024, 1024);
  wt_kernel<<<dim3(1024/32, 1024/32), tb, 0, stream>>>(Wo, WoT, 1024, 1024);
  wt_kernel<<<dim3(4096/32, 1024/32), tb, 0, stream>>>(W1, W1T, 1024, 4096);
  wt_kernel<<<dim3(1024/32, 4096/32), tb, 0, stream>>>(W2, W2T, 4096, 1024);

  ln_kernel<<<ROWS, tb, 0, stream>>>(x, g1, be1, hln);

  // fused QKV: one GEMM over [3072][1024] weights, routed epilogue (q pre-scaled)
  gemm_bt<3><<<dim3(3072/128, ROWS/128), tb, 0, stream>>>(hln, WqkvT, bq, nullptr, qb,
                                                          ROWS, 3072, 1024,
                                                          bk, bv, kb, vb);

  vtrans_kernel<<<dim3(SEQ/64, BATCH*NHEAD), tb, 0, stream>>>(vb, vt);

  attn_kernel<<<dim3(SEQ/128, BATCH*NHEAD), tb, 0, stream>>>(qb, kb, vt, mask, attn);

  gemm_bt<1><<<dim3(1024/128, ROWS/128), tb, 0, stream>>>(attn, WoT, bo, x, x2,
                                                          ROWS, 1024, 1024,
                                                          nullptr, nullptr, nullptr, nullptr);

  ln_kernel<<<ROWS, tb, 0, stream>>>(x2, g2, be2, hln);

  gemm_bt<2><<<dim3(4096/128, ROWS/128), tb, 0, stream>>>(hln, W1T, b1, nullptr, ff1,
                                                          ROWS, 4096, 1024,
                                                          nullptr, nullptr, nullptr, nullptr);

  gemm_bt<1><<<dim3(1024/128, ROWS/128), tb, 0, stream>>>(ff1, W2T, b2, x2, (float*)d_out,
                                                          ROWS, 1024, 4096,
                                                          nullptr, nullptr, nullptr, nullptr);
}